// Round 3
// baseline (303.791 us; speedup 1.0000x reference)
//
#include <hip/hip_runtime.h>

// Fused: per-channel affine+relu -> dilated(2) 3x3 box-sum (zero pad) ->
// sigmoid gate -> multiply -> 2x nearest upsample -> add y.
//
// One thread owns an 8-pixel strip of one input row. All global loads
// (3 x-rows as 2xfloat4+2xfloat2 each, plus 8 y float4s) are issued up
// front to maximize bytes-in-flight (R1 post-mortem: 16-VGPR scalar-load
// version was MLP-starved at 2.4 TB/s). Stores are nontemporal (out is
// never re-read). R2 fix: nontemporal builtin needs a native vector type,
// not HIP_vector_type — use ext_vector_type(4).

#define DIA 2

typedef float floatx4 __attribute__((ext_vector_type(4)));

__global__ __launch_bounds__(256) void fused_kernel(
    const float* __restrict__ x, const float* __restrict__ y,
    const float* __restrict__ w1v, const float* __restrict__ b1v,
    const float* __restrict__ w2v, const float* __restrict__ b2v,
    float* __restrict__ out)
{
    constexpr int C = 3, H = 512, W = 512, W2 = 1024;

    int idx = blockIdx.x * blockDim.x + threadIdx.x;
    int t  = idx & 63;                                   // lane: strip id, row = wave
    int h  = __builtin_amdgcn_readfirstlane((idx >> 6) & (H - 1));
    int bc = __builtin_amdgcn_readfirstlane(idx >> 15);  // 0..23 (b*C + c)
    int c  = bc % C;
    int w0 = t << 3;                                     // 0..504

    const float s_w1 = w1v[c], s_b1 = b1v[c];
    const float s_w2 = w2v[c], s_b2 = b2v[c];

    const float* __restrict__ xrow = x + ((size_t)bc * H + (size_t)h) * W + w0;
    const float* r0 = xrow - DIA * W;
    const float* r2 = xrow + DIA * W;

    const bool lok = (t > 0), rok = (t < 63);
    const bool ok0 = (h >= DIA), ok2 = (h < H - DIA);
    const float mlf = lok ? 1.f : 0.f;
    const float mrf = rok ? 1.f : 0.f;
    const float m0  = ok0 ? 1.f : 0.f;
    const float m2  = ok2 ? 1.f : 0.f;

    const float2 Z2 = make_float2(0.f, 0.f);
    const float4 Z4 = make_float4(0.f, 0.f, 0.f, 0.f);

    // ---- issue ALL global loads up front ----
    float2 L1 = lok ? *(const float2*)(xrow - 2) : Z2;
    float4 A1 = *(const float4*)(xrow);
    float4 B1 = *(const float4*)(xrow + 4);
    float2 R1 = rok ? *(const float2*)(xrow + 8) : Z2;

    float2 L0 = (ok0 && lok) ? *(const float2*)(r0 - 2) : Z2;
    float4 A0 = ok0 ? *(const float4*)(r0) : Z4;
    float4 B0 = ok0 ? *(const float4*)(r0 + 4) : Z4;
    float2 R0 = (ok0 && rok) ? *(const float2*)(r0 + 8) : Z2;

    float2 L2 = (ok2 && lok) ? *(const float2*)(r2 - 2) : Z2;
    float4 A2 = ok2 ? *(const float4*)(r2) : Z4;
    float4 B2 = ok2 ? *(const float4*)(r2 + 4) : Z4;
    float2 R2 = (ok2 && rok) ? *(const float2*)(r2 + 8) : Z2;

    size_t obase = (((size_t)bc * (2 * H) + (size_t)(2 * h)) * W2) + (size_t)(w0 << 1);
    const float* yp0 = y + obase;
    const float* yp1 = yp0 + W2;
    float4 y00 = *(const float4*)(yp0);
    float4 y01 = *(const float4*)(yp0 + 4);
    float4 y02 = *(const float4*)(yp0 + 8);
    float4 y03 = *(const float4*)(yp0 + 12);
    float4 y10 = *(const float4*)(yp1);
    float4 y11 = *(const float4*)(yp1 + 4);
    float4 y12 = *(const float4*)(yp1 + 8);
    float4 y13 = *(const float4*)(yp1 + 12);

    // ---- compute ----
    float vs[8] = {0.f,0.f,0.f,0.f,0.f,0.f,0.f,0.f};
    float ctr[8];

    auto row = [&](float2 L, float4 A, float4 B, float2 R,
                   float mL, float mM, float mR, float* center) {
        float a[12];
        a[0]  = mL * fmaxf(fmaf(L.x, s_w1, s_b1), 0.f);
        a[1]  = mL * fmaxf(fmaf(L.y, s_w1, s_b1), 0.f);
        a[2]  = mM * fmaxf(fmaf(A.x, s_w1, s_b1), 0.f);
        a[3]  = mM * fmaxf(fmaf(A.y, s_w1, s_b1), 0.f);
        a[4]  = mM * fmaxf(fmaf(A.z, s_w1, s_b1), 0.f);
        a[5]  = mM * fmaxf(fmaf(A.w, s_w1, s_b1), 0.f);
        a[6]  = mM * fmaxf(fmaf(B.x, s_w1, s_b1), 0.f);
        a[7]  = mM * fmaxf(fmaf(B.y, s_w1, s_b1), 0.f);
        a[8]  = mM * fmaxf(fmaf(B.z, s_w1, s_b1), 0.f);
        a[9]  = mM * fmaxf(fmaf(B.w, s_w1, s_b1), 0.f);
        a[10] = mR * fmaxf(fmaf(R.x, s_w1, s_b1), 0.f);
        a[11] = mR * fmaxf(fmaf(R.y, s_w1, s_b1), 0.f);
        if (center) {
            #pragma unroll
            for (int p = 0; p < 8; ++p) center[p] = a[p + 2];
        }
        #pragma unroll
        for (int p = 0; p < 8; ++p) vs[p] += a[p] + a[p + 2] + a[p + 4];
    };

    row(L0, A0, B0, R0, m0 * mlf, m0, m0 * mrf, nullptr);
    row(L1, A1, B1, R1, mlf,      1.f, mrf,     ctr);
    row(L2, A2, B2, R2, m2 * mlf, m2, m2 * mrf, nullptr);

    float o[8];
    #pragma unroll
    for (int p = 0; p < 8; ++p) {
        float zv = fmaf(vs[p], s_w2, s_b2);
        float g  = 1.f / (1.f + __expf(-zv));
        o[p] = g * ctr[p];
    }

    // ---- 2x nearest upsample + add y, nontemporal stores ----
    float* op0 = out + obase;
    float* op1 = op0 + W2;
    auto nt4 = [](float* p, float a, float b, float c2, float d) {
        floatx4 v = {a, b, c2, d};
        __builtin_nontemporal_store(v, (floatx4*)p);
    };
    nt4(op0,      y00.x+o[0], y00.y+o[0], y00.z+o[1], y00.w+o[1]);
    nt4(op0 + 4,  y01.x+o[2], y01.y+o[2], y01.z+o[3], y01.w+o[3]);
    nt4(op0 + 8,  y02.x+o[4], y02.y+o[4], y02.z+o[5], y02.w+o[5]);
    nt4(op0 + 12, y03.x+o[6], y03.y+o[6], y03.z+o[7], y03.w+o[7]);
    nt4(op1,      y10.x+o[0], y10.y+o[0], y10.z+o[1], y10.w+o[1]);
    nt4(op1 + 4,  y11.x+o[2], y11.y+o[2], y11.z+o[3], y11.w+o[3]);
    nt4(op1 + 8,  y12.x+o[4], y12.y+o[4], y12.z+o[5], y12.w+o[5]);
    nt4(op1 + 12, y13.x+o[6], y13.y+o[6], y13.z+o[7], y13.w+o[7]);
}

extern "C" void kernel_launch(void* const* d_in, const int* in_sizes, int n_in,
                              void* d_out, int out_size, void* d_ws, size_t ws_size,
                              hipStream_t stream) {
    const float* x  = (const float*)d_in[0];
    const float* y  = (const float*)d_in[1];
    const float* w1 = (const float*)d_in[2];
    const float* b1 = (const float*)d_in[3];
    const float* w2 = (const float*)d_in[4];
    const float* b2 = (const float*)d_in[5];
    float* out = (float*)d_out;

    constexpr int B = 8, C = 3, H = 512, W = 512;
    int total_threads = B * C * H * (W / 8);   // 786,432
    int block = 256;
    int grid  = total_threads / block;         // 3,072
    fused_kernel<<<grid, block, 0, stream>>>(x, y, w1, b1, w2, b2, out);
}

// Round 4
// 212.473 us; speedup vs baseline: 1.4298x; 1.4298x over previous
//
#include <hip/hip_runtime.h>

// Fused: per-channel affine+relu -> dilated(2) 3x3 box-sum (zero pad) ->
// sigmoid gate -> multiply -> 2x nearest upsample -> add y.
//
// One thread owns an 8-pixel strip of one input row (wave = one row).
// R3 post-mortem: nontemporal 16B stores on a 256B lane stride caused 2.5x
// HBM write amplification (nt defeats L2 write-combining of partial lines)
// -> plain cached stores here. Loads are UNCONDITIONAL with clamped
// addresses (no exec-mask branches) so all ~20 global_load instructions
// issue back-to-back; boundary zeroing is done arithmetically post-relu.

#define DIA 2

__global__ __launch_bounds__(256) void fused_kernel(
    const float* __restrict__ x, const float* __restrict__ y,
    const float* __restrict__ w1v, const float* __restrict__ b1v,
    const float* __restrict__ w2v, const float* __restrict__ b2v,
    float* __restrict__ out)
{
    constexpr int C = 3, H = 512, W = 512, W2 = 1024;

    int idx = blockIdx.x * blockDim.x + threadIdx.x;
    int t  = idx & 63;                                   // lane: strip id, row = wave
    int h  = __builtin_amdgcn_readfirstlane((idx >> 6) & (H - 1));
    int bc = __builtin_amdgcn_readfirstlane(idx >> 15);  // 0..23 (b*C + c)
    int c  = bc % C;
    int w0 = t << 3;                                     // 0..504

    const float s_w1 = w1v[c], s_b1 = b1v[c];
    const float s_w2 = w2v[c], s_b2 = b2v[c];

    const float* __restrict__ xrow = x + ((size_t)bc * H + (size_t)h) * W + w0;

    const bool lok = (t > 0), rok = (t < 63);
    const bool ok0 = (h >= DIA), ok2 = (h < H - DIA);
    const float mlf = lok ? 1.f : 0.f;
    const float mrf = rok ? 1.f : 0.f;
    const float m0  = ok0 ? 1.f : 0.f;
    const float m2  = ok2 ? 1.f : 0.f;

    // Clamped (always in-bounds) base pointers; masked arithmetically later.
    const float* r0 = ok0 ? (xrow - DIA * W) : xrow;
    const float* r2 = ok2 ? (xrow + DIA * W) : xrow;
    const float* pL1 = lok ? (xrow - 2) : xrow;
    const float* pR1 = rok ? (xrow + 8) : xrow;
    const float* pL0 = lok ? (r0 - 2) : r0;
    const float* pR0 = rok ? (r0 + 8) : r0;
    const float* pL2 = lok ? (r2 - 2) : r2;
    const float* pR2 = rok ? (r2 + 8) : r2;

    // ---- issue ALL global loads up front, unconditionally ----
    float2 L1 = *(const float2*)(pL1);
    float4 A1 = *(const float4*)(xrow);
    float4 B1 = *(const float4*)(xrow + 4);
    float2 R1 = *(const float2*)(pR1);

    float2 L0 = *(const float2*)(pL0);
    float4 A0 = *(const float4*)(r0);
    float4 B0 = *(const float4*)(r0 + 4);
    float2 R0 = *(const float2*)(pR0);

    float2 L2 = *(const float2*)(pL2);
    float4 A2 = *(const float4*)(r2);
    float4 B2 = *(const float4*)(r2 + 4);
    float2 R2 = *(const float2*)(pR2);

    size_t obase = (((size_t)bc * (2 * H) + (size_t)(2 * h)) * W2) + (size_t)(w0 << 1);
    const float* yp0 = y + obase;
    const float* yp1 = yp0 + W2;
    float4 y00 = *(const float4*)(yp0);
    float4 y01 = *(const float4*)(yp0 + 4);
    float4 y02 = *(const float4*)(yp0 + 8);
    float4 y03 = *(const float4*)(yp0 + 12);
    float4 y10 = *(const float4*)(yp1);
    float4 y11 = *(const float4*)(yp1 + 4);
    float4 y12 = *(const float4*)(yp1 + 8);
    float4 y13 = *(const float4*)(yp1 + 12);

    // ---- compute ----
    float vs[8] = {0.f,0.f,0.f,0.f,0.f,0.f,0.f,0.f};
    float ctr[8];

    auto row = [&](float2 L, float4 A, float4 B, float2 R,
                   float mL, float mM, float mR, float* center) {
        float a[12];
        a[0]  = mL * fmaxf(fmaf(L.x, s_w1, s_b1), 0.f);
        a[1]  = mL * fmaxf(fmaf(L.y, s_w1, s_b1), 0.f);
        a[2]  = mM * fmaxf(fmaf(A.x, s_w1, s_b1), 0.f);
        a[3]  = mM * fmaxf(fmaf(A.y, s_w1, s_b1), 0.f);
        a[4]  = mM * fmaxf(fmaf(A.z, s_w1, s_b1), 0.f);
        a[5]  = mM * fmaxf(fmaf(A.w, s_w1, s_b1), 0.f);
        a[6]  = mM * fmaxf(fmaf(B.x, s_w1, s_b1), 0.f);
        a[7]  = mM * fmaxf(fmaf(B.y, s_w1, s_b1), 0.f);
        a[8]  = mM * fmaxf(fmaf(B.z, s_w1, s_b1), 0.f);
        a[9]  = mM * fmaxf(fmaf(B.w, s_w1, s_b1), 0.f);
        a[10] = mR * fmaxf(fmaf(R.x, s_w1, s_b1), 0.f);
        a[11] = mR * fmaxf(fmaf(R.y, s_w1, s_b1), 0.f);
        if (center) {
            #pragma unroll
            for (int p = 0; p < 8; ++p) center[p] = a[p + 2];
        }
        #pragma unroll
        for (int p = 0; p < 8; ++p) vs[p] += a[p] + a[p + 2] + a[p + 4];
    };

    row(L0, A0, B0, R0, m0 * mlf, m0, m0 * mrf, nullptr);
    row(L1, A1, B1, R1, mlf,      1.f, mrf,     ctr);
    row(L2, A2, B2, R2, m2 * mlf, m2, m2 * mrf, nullptr);

    float o[8];
    #pragma unroll
    for (int p = 0; p < 8; ++p) {
        float zv = fmaf(vs[p], s_w2, s_b2);
        float g  = 1.f / (1.f + __expf(-zv));
        o[p] = g * ctr[p];
    }

    // ---- 2x nearest upsample + add y, plain cached stores ----
    float* op0 = out + obase;
    float* op1 = op0 + W2;
    *(float4*)(op0)      = make_float4(y00.x+o[0], y00.y+o[0], y00.z+o[1], y00.w+o[1]);
    *(float4*)(op0 + 4)  = make_float4(y01.x+o[2], y01.y+o[2], y01.z+o[3], y01.w+o[3]);
    *(float4*)(op0 + 8)  = make_float4(y02.x+o[4], y02.y+o[4], y02.z+o[5], y02.w+o[5]);
    *(float4*)(op0 + 12) = make_float4(y03.x+o[6], y03.y+o[6], y03.z+o[7], y03.w+o[7]);
    *(float4*)(op1)      = make_float4(y10.x+o[0], y10.y+o[0], y10.z+o[1], y10.w+o[1]);
    *(float4*)(op1 + 4)  = make_float4(y11.x+o[2], y11.y+o[2], y11.z+o[3], y11.w+o[3]);
    *(float4*)(op1 + 8)  = make_float4(y12.x+o[4], y12.y+o[4], y12.z+o[5], y12.w+o[5]);
    *(float4*)(op1 + 12) = make_float4(y13.x+o[6], y13.y+o[6], y13.z+o[7], y13.w+o[7]);
}

extern "C" void kernel_launch(void* const* d_in, const int* in_sizes, int n_in,
                              void* d_out, int out_size, void* d_ws, size_t ws_size,
                              hipStream_t stream) {
    const float* x  = (const float*)d_in[0];
    const float* y  = (const float*)d_in[1];
    const float* w1 = (const float*)d_in[2];
    const float* b1 = (const float*)d_in[3];
    const float* w2 = (const float*)d_in[4];
    const float* b2 = (const float*)d_in[5];
    float* out = (float*)d_out;

    constexpr int B = 8, C = 3, H = 512, W = 512;
    int total_threads = B * C * H * (W / 8);   // 786,432
    int block = 256;
    int grid  = total_threads / block;         // 3,072
    fused_kernel<<<grid, block, 0, stream>>>(x, y, w1, b1, w2, b2, out);
}

// Round 5
// 198.586 us; speedup vs baseline: 1.5298x; 1.0699x over previous
//
#include <hip/hip_runtime.h>

// Fused: per-channel affine+relu -> dilated(2) 3x3 box-sum (zero pad) ->
// sigmoid gate -> multiply -> 2x nearest upsample -> add y.
//
// Mapping: 1 thread = 2 adjacent input pixels (w0, w0+1) -> 4x2 output block.
// Lanes stride 16 B on y/out so every float4 load/store instruction is fully
// contiguous across the wave (R4 post-mortem: 8-pixel strips made each
// y/out dwordx4 instruction touch 64 cache lines instead of 16 -> VMEM
// request-bound at 2.5 TB/s).
// x taps: 3 float2 loads per row (w0-2..w0+3), UNCONDITIONAL with clamped
// addresses (no exec-mask branches; R3 post-mortem), masked arithmetically
// post-relu. Plain cached stores (nt caused 2.5x write amplification).

#define DIA 2

__global__ __launch_bounds__(256) void fused_kernel(
    const float* __restrict__ x, const float* __restrict__ y,
    const float* __restrict__ w1v, const float* __restrict__ b1v,
    const float* __restrict__ w2v, const float* __restrict__ b2v,
    float* __restrict__ out)
{
    constexpr int C = 3, H = 512, W = 512, W2 = 1024;

    int idx = blockIdx.x * blockDim.x + threadIdx.x;
    int wp = idx & (W / 2 - 1);                              // 0..255, lane-contiguous
    int h  = __builtin_amdgcn_readfirstlane((idx >> 8) & (H - 1));
    int bc = __builtin_amdgcn_readfirstlane(idx >> 17);      // 0..23 (b*C + c)
    int c  = bc % C;
    int w0 = wp * 2;                                         // even, 0..510

    const float s_w1 = w1v[c], s_b1 = b1v[c];
    const float s_w2 = w2v[c], s_b2 = b2v[c];

    const float* __restrict__ xrow = x + ((size_t)bc * H + (size_t)h) * W;

    const bool ok0 = (h >= DIA), ok2 = (h < H - DIA);
    const bool lok = (w0 > 0), rok = (w0 + 2 < W);
    const float m0 = ok0 ? 1.f : 0.f;
    const float m2 = ok2 ? 1.f : 0.f;
    const float mL = lok ? 1.f : 0.f;
    const float mR = rok ? 1.f : 0.f;

    // Clamped, always-in-bounds addresses (8B-aligned: offsets all even).
    const float* r1 = xrow;
    const float* r0 = ok0 ? (xrow - DIA * W) : xrow;
    const float* r2 = ok2 ? (xrow + DIA * W) : xrow;
    const int wl = lok ? (w0 - 2) : w0;
    const int wr = rok ? (w0 + 2) : w0;

    // ---- issue ALL global loads up front, unconditionally ----
    float2 L0 = *(const float2*)(r0 + wl);
    float2 M0 = *(const float2*)(r0 + w0);
    float2 R0 = *(const float2*)(r0 + wr);
    float2 L1 = *(const float2*)(r1 + wl);
    float2 M1 = *(const float2*)(r1 + w0);
    float2 R1 = *(const float2*)(r1 + wr);
    float2 L2 = *(const float2*)(r2 + wl);
    float2 M2 = *(const float2*)(r2 + w0);
    float2 R2 = *(const float2*)(r2 + wr);

    size_t obase = (((size_t)bc * (2 * H) + (size_t)(2 * h)) * W2) + (size_t)(2 * w0);
    float4 ya = *(const float4*)(y + obase);
    float4 yb = *(const float4*)(y + obase + W2);

    // ---- compute ----
    auto act = [&](float v) { return fmaxf(fmaf(v, s_w1, s_b1), 0.f); };

    // center (= x_r): always valid
    float xo0 = act(M1.x);
    float xo1 = act(M1.y);

    float sum0 = mL * act(L1.x) + xo0 + mR * act(R1.x);
    float sum1 = mL * act(L1.y) + xo1 + mR * act(R1.y);
    sum0 += m0 * (mL * act(L0.x) + act(M0.x) + mR * act(R0.x));
    sum1 += m0 * (mL * act(L0.y) + act(M0.y) + mR * act(R0.y));
    sum0 += m2 * (mL * act(L2.x) + act(M2.x) + mR * act(R2.x));
    sum1 += m2 * (mL * act(L2.y) + act(M2.y) + mR * act(R2.y));

    float z0 = fmaf(sum0, s_w2, s_b2);
    float z1 = fmaf(sum1, s_w2, s_b2);
    float o0 = xo0 / (1.f + __expf(-z0));
    float o1 = xo1 / (1.f + __expf(-z1));

    // ---- 2x nearest upsample + add y (lane-contiguous float4 stores) ----
    *(float4*)(out + obase)      = make_float4(ya.x + o0, ya.y + o0, ya.z + o1, ya.w + o1);
    *(float4*)(out + obase + W2) = make_float4(yb.x + o0, yb.y + o0, yb.z + o1, yb.w + o1);
}

extern "C" void kernel_launch(void* const* d_in, const int* in_sizes, int n_in,
                              void* d_out, int out_size, void* d_ws, size_t ws_size,
                              hipStream_t stream) {
    const float* x  = (const float*)d_in[0];
    const float* y  = (const float*)d_in[1];
    const float* w1 = (const float*)d_in[2];
    const float* b1 = (const float*)d_in[3];
    const float* w2 = (const float*)d_in[4];
    const float* b2 = (const float*)d_in[5];
    float* out = (float*)d_out;

    constexpr int B = 8, C = 3, H = 512, W = 512;
    int total_threads = B * C * H * (W / 2);   // 3,145,728
    int block = 256;
    int grid  = total_threads / block;         // 12,288
    fused_kernel<<<grid, block, 0, stream>>>(x, y, w1, b1, w2, b2, out);
}